// Round 7
// baseline (4972.482 us; speedup 1.0000x reference)
//
#include <hip/hip_runtime.h>
#include <math.h>

#define T_STEPS 1024
#define BATCH   512
#define DZ      256
#define DH      256
#define RANK    8
#define DY      16

// 512 blocks x 512 threads (8 waves), 1 batch element/block -> 2 blocks/CU
// (16 waves/CU): all 256 CUs active; the co-resident block hides barrier
// stalls. R5's 3-barrier structure (numerically validated, absmax 0.0039):
//   A -> {dot2 partials, out(t-1), tanh(h)@V} -> B
//     -> {z-update (waves 0-3) || rz/sig/gl (waves 4-7)} -> C
//     -> {h-update, input publish} -> A
// Thread (i=tid&255, q2=tid>>8) holds f16-packed W_zz[i,128q2..+128] (64
// VGPR) + Wz_in (16) + W_in (8), consumed by v_dot2_f32_f16 (f32 accum).
// 512-thread blocks get a 128-VGPR budget (R6: 112), unlike 1024-thread
// blocks which are capped at 64 (R1-R4) or 32 (R5) -> no spills.
// Incremental signal projection rz = z@wzo[r] (R5) removes the
// z-publish->signal->h barrier chain.

typedef _Float16 f16;
typedef _Float16 h2 __attribute__((ext_vector_type(2)));

__device__ __forceinline__ h2 pack2(float a, float b) {
    h2 r; r.x = (f16)a; r.y = (f16)b; return r;
}
__device__ __forceinline__ h2 bc(unsigned u) { return __builtin_bit_cast(h2, u); }

__device__ __forceinline__ float dot2(h2 a, h2 b, float c) {
#if __has_builtin(__builtin_amdgcn_fdot2)
    return __builtin_amdgcn_fdot2(a, b, c, false);
#else
    return fmaf((float)a.x, (float)b.x, fmaf((float)a.y, (float)b.y, c));
#endif
}

__device__ __forceinline__ float fast_tanh(float x) {
    const float e = __expf(2.0f * x);
    return 1.0f - 2.0f / (e + 1.0f);
}

__global__ __launch_bounds__(512, 4)
void nmrnn_kernel(
    const float* __restrict__ s, const float* __restrict__ c,
    const float* __restrict__ W_zz, const float* __restrict__ Wz_in,
    const float* __restrict__ bz_in, const float* __restrict__ Wz_out,
    const float* __restrict__ bz_out, const float* __restrict__ U,
    const float* __restrict__ V, const float* __restrict__ W_in,
    const float* __restrict__ b_in, const float* __restrict__ W_out,
    const float* __restrict__ b_out,
    float* __restrict__ out, float* __restrict__ states)
{
    __shared__ __align__(16) f16 tzh[DZ];       // tanh(z) f16
    __shared__ __align__(16) f16 sclh[64];      // [s_t|c_t] f16
    __shared__ __align__(16) float th[DH];      // tanh(h) f32
    __shared__ __align__(16) float redz[2][DZ]; // z-dot partials
    __shared__ __align__(16) float redh[2][DZ]; // W_in-dot partials
    __shared__ __align__(16) float wzo[RANK][DZ];
    __shared__ __align__(16) float vt[RANK][DH];  // V^T
    __shared__ __align__(16) float ut[RANK][DH];  // U^T
    __shared__ __align__(16) float wo[DY][DH];    // W_out
    __shared__ float gl[RANK];
    __shared__ float bo[DY];

    const int tid  = threadIdx.x;
    const int i    = tid & 255;
    const int q2   = tid >> 8;     // 0..1  K-half
    const int g    = tid >> 6;     // 0..7  wave
    const int l    = tid & 63;
    const int half = l >> 5;
    const int l32  = l & 31;
    const int b    = blockIdx.x;

    // ---- persistent f16-packed weights (88 VGPRs) ----
    h2 wzzp[64];
    #pragma unroll
    for (int m = 0; m < 32; ++m) {
        const float4 v4 = *(const float4*)&W_zz[i * 256 + (q2 << 7) + (m << 2)];
        wzzp[2 * m]     = pack2(v4.x, v4.y);
        wzzp[2 * m + 1] = pack2(v4.z, v4.w);
    }
    h2 wzip[16];
    #pragma unroll
    for (int m = 0; m < 8; ++m) {
        const float4 v4 = *(const float4*)&Wz_in[i * 64 + (q2 << 5) + (m << 2)];
        wzip[2 * m]     = pack2(v4.x, v4.y);
        wzip[2 * m + 1] = pack2(v4.z, v4.w);
    }
    h2 wip[8];
    #pragma unroll
    for (int m = 0; m < 4; ++m) {
        const float4 v4 = *(const float4*)&W_in[i * 32 + (q2 << 4) + (m << 2)];
        wip[2 * m]     = pack2(v4.x, v4.y);
        wip[2 * m + 1] = pack2(v4.z, v4.w);
    }

    // ---- stage small f32 matrices ----
    {   // Wz_out: 2048 floats
        const float4 v4 = *(const float4*)&Wz_out[tid * 4];
        *(float4*)&((float*)wzo)[tid * 4] = v4;
    }
    #pragma unroll
    for (int it = 0; it < 2; ++it) {  // W_out: 4096 floats
        const int idx = tid * 4 + it * 2048;
        *(float4*)&((float*)wo)[idx] = *(const float4*)&W_out[idx];
    }
    if (tid < 256) {
        #pragma unroll
        for (int r = 0; r < RANK; ++r) vt[r][tid] = V[tid * RANK + r];
        #pragma unroll
        for (int r = 0; r < RANK; ++r) ut[r][tid] = U[tid * RANK + r];
        tzh[tid] = (f16)0.f; th[tid] = 0.f;
    }
    if (tid < DY) bo[tid] = b_out[tid];

    const float bzi = (tid < 256) ? bz_in[i] : 0.f;
    const float bi  = (tid < 256) ? b_in[i]  : 0.f;
    float z_r = 0.f, h_r = 0.f;
    __syncthreads();   // staging done (wzo needed below)

    // ---- waves 4-7 persistent: rank rr, czb, rzb ----
    int rr = 0;
    float czb = 0.f, rzb = 0.f, hp = 0.f;
    if (g >= 4) {
        rr = ((g - 4) << 1) | half;
        float cz = 0.f;
        #pragma unroll
        for (int m = 0; m < 8; ++m) {
            const int k = l32 + 32 * m;
            cz = fmaf(bz_in[k], wzo[rr][k], cz);
        }
        #pragma unroll
        for (int off = 16; off >= 1; off >>= 1) cz += __shfl_xor(cz, off);
        const float bzo_r = bz_out[rr];
        czb = cz + bzo_r;
        rzb = bzo_r;
    }

    // t=0 inputs
    if (tid < 64) {
        const size_t base = (size_t)b * 32;
        sclh[tid] = (f16)((l < 32) ? s[base + l] : c[base + l - 32]);
    }
    __syncthreads();   // A0

    for (int t = 0; t < T_STEPS; ++t) {
        // ================= A..B =================
        float pfn = 0.f;
        if (tid < 64 && t + 1 < T_STEPS) {  // prefetch next inputs
            const size_t base = ((size_t)(t + 1) * BATCH + b) * 32;
            pfn = (l < 32) ? s[base + l] : c[base + l - 32];
        }

        // hp = tanh(h_{t-1}) @ V[:,rr]  (waves 4-7, 32-lane groups)
        if (g >= 4) {
            hp = 0.f;
            #pragma unroll
            for (int m = 0; m < 8; ++m) {
                const int k = l32 + 32 * m;
                hp = fmaf(th[k], vt[rr][k], hp);
            }
            #pragma unroll
            for (int off = 16; off >= 1; off >>= 1) hp += __shfl_xor(hp, off);
        }

        // out(t-1): 16 y-groups of 32 lanes, all waves
        if (t > 0) {
            const int y = (g << 1) | half;
            float o = 0.f;
            #pragma unroll
            for (int m = 0; m < 8; ++m) {
                const int k = l32 + 32 * m;
                o = fmaf(th[k], wo[y][k], o);
            }
            #pragma unroll
            for (int off = 16; off >= 1; off >>= 1) o += __shfl_xor(o, off);
            if (l32 == 0) out[((size_t)(t - 1) * BATCH + b) * 16 + y] = o + bo[y];
        }

        // dot2 partials: W_zz K-half + Wz_in + W_in (uniform LDS broadcasts)
        {
            float az = 0.f, ah = 0.f;
            const uint4* tz = (const uint4*)&tzh[q2 << 7];
            #pragma unroll
            for (int m = 0; m < 16; ++m) {
                const uint4 u = tz[m];
                az = dot2(wzzp[4 * m + 0], bc(u.x), az);
                az = dot2(wzzp[4 * m + 1], bc(u.y), az);
                az = dot2(wzzp[4 * m + 2], bc(u.z), az);
                az = dot2(wzzp[4 * m + 3], bc(u.w), az);
            }
            const uint4* sp = (const uint4*)&sclh[q2 << 5];
            #pragma unroll
            for (int m = 0; m < 4; ++m) {
                const uint4 u = sp[m];
                az = dot2(wzip[4 * m + 0], bc(u.x), az);
                az = dot2(wzip[4 * m + 1], bc(u.y), az);
                az = dot2(wzip[4 * m + 2], bc(u.z), az);
                az = dot2(wzip[4 * m + 3], bc(u.w), az);
            }
            const uint4* wp = (const uint4*)&sclh[q2 << 4];
            #pragma unroll
            for (int m = 0; m < 2; ++m) {
                const uint4 u = wp[m];
                ah = dot2(wip[4 * m + 0], bc(u.x), ah);
                ah = dot2(wip[4 * m + 1], bc(u.y), ah);
                ah = dot2(wip[4 * m + 2], bc(u.z), ah);
                ah = dot2(wip[4 * m + 3], bc(u.w), ah);
            }
            redz[q2][i] = az;
            redh[q2][i] = ah;
        }
        __syncthreads();  // B

        // ================= B..C =================
        if (tid < 256) {
            const float tmp = redz[0][i] + redz[1][i] + bzi;
            z_r = 0.99f * z_r + 0.01f * tmp;
            tzh[i] = (f16)fast_tanh(z_r);
            states[((size_t)t * BATCH + b) * 512 + i] = z_r;
        } else {
            float zp = 0.f;
            #pragma unroll
            for (int m = 0; m < 8; ++m) {
                const int k = l32 + 32 * m;
                zp = fmaf(redz[0][k] + redz[1][k], wzo[rr][k], zp);
            }
            #pragma unroll
            for (int off = 16; off >= 1; off >>= 1) zp += __shfl_xor(zp, off);
            rzb = 0.99f * rzb + 0.01f * (zp + czb);
            const float sg = 1.0f / (1.0f + __expf(-rzb));
            if (l32 == 0) gl[rr] = sg * hp;
        }
        __syncthreads();  // C

        // ================= C..A' =================
        if (tid < 256) {
            float tmp = redh[0][i] + redh[1][i] + bi;
            #pragma unroll
            for (int r = 0; r < RANK; ++r) tmp = fmaf(ut[r][i], gl[r], tmp);
            h_r = 0.9f * h_r + 0.1f * tmp;
            th[i] = fast_tanh(h_r);
            states[((size_t)t * BATCH + b) * 512 + 256 + i] = h_r;
        }
        if (tid < 64 && t + 1 < T_STEPS) sclh[tid] = (f16)pfn;
        __syncthreads();  // A
    }

    // ---- final out (t = T_STEPS-1) ----
    {
        const int y = (g << 1) | half;
        float o = 0.f;
        #pragma unroll
        for (int m = 0; m < 8; ++m) {
            const int k = l32 + 32 * m;
            o = fmaf(th[k], wo[y][k], o);
        }
        #pragma unroll
        for (int off = 16; off >= 1; off >>= 1) o += __shfl_xor(o, off);
        if (l32 == 0) out[((size_t)(T_STEPS - 1) * BATCH + b) * 16 + y] = o + bo[y];
    }
}

extern "C" void kernel_launch(void* const* d_in, const int* in_sizes, int n_in,
                              void* d_out, int out_size, void* d_ws, size_t ws_size,
                              hipStream_t stream) {
    const float* s     = (const float*)d_in[0];
    const float* c     = (const float*)d_in[1];
    const float* W_zz  = (const float*)d_in[2];
    const float* Wz_in = (const float*)d_in[3];
    const float* bz_in = (const float*)d_in[4];
    const float* Wz_out= (const float*)d_in[5];
    const float* bz_out= (const float*)d_in[6];
    const float* U     = (const float*)d_in[7];
    const float* V     = (const float*)d_in[8];
    const float* W_in  = (const float*)d_in[9];
    const float* b_in  = (const float*)d_in[10];
    const float* W_out = (const float*)d_in[11];
    const float* b_out = (const float*)d_in[12];

    float* out    = (float*)d_out;
    float* states = out + (size_t)T_STEPS * BATCH * DY;

    hipLaunchKernelGGL(nmrnn_kernel, dim3(BATCH), dim3(512), 0, stream,
                       s, c, W_zz, Wz_in, bz_in, Wz_out, bz_out, U, V,
                       W_in, b_in, W_out, b_out, out, states);
}

// Round 8
// 3497.950 us; speedup vs baseline: 1.4215x; 1.4215x over previous
//
#include <hip/hip_runtime.h>
#include <math.h>

#define T_STEPS 1024
#define BATCH   512
#define DZ      256
#define DH      256
#define RANK    8
#define DY      16

// 512 blocks x 512 threads (8 waves), 1 batch element/block -> 2 blocks/CU
// (16 waves/CU): all 256 CUs active; the co-resident block hides barrier
// stalls. 3-barrier structure (numerically validated, absmax 0.0039):
//   A -> {dot2 partials, out(t-1), tanh(h)@V} -> B
//     -> {z-update (waves 0-3) || rz/sig/gl (waves 4-7)} -> C
//     -> {h-update, input publish} -> A
// Thread (i=tid&255, q2=tid>>8) holds f16-packed W_zz[i,128q2..+128] (64
// VGPR) + Wz_in (16) + W_in (8), consumed by v_dot2_f32_f16 (f32 accum).
//
// REGISTER INCANTATION (the whole game, R1-R7): __launch_bounds__'s 2nd arg
// behaves as min-BLOCKS-per-CU: (512,4) -> 32 waves/CU -> 64-VGPR cap ->
// spills (R7, 4.97ms); (512,2) -> 16 waves/CU -> 128 budget -> 112 VGPRs,
// no spills (R6, verified). Use exactly (512, 2). Do not touch.

typedef _Float16 f16;
typedef _Float16 h2 __attribute__((ext_vector_type(2)));

__device__ __forceinline__ h2 pack2(float a, float b) {
    h2 r; r.x = (f16)a; r.y = (f16)b; return r;
}
__device__ __forceinline__ h2 bc(unsigned u) { return __builtin_bit_cast(h2, u); }

__device__ __forceinline__ float dot2(h2 a, h2 b, float c) {
#if __has_builtin(__builtin_amdgcn_fdot2)
    return __builtin_amdgcn_fdot2(a, b, c, false);
#else
    return fmaf((float)a.x, (float)b.x, fmaf((float)a.y, (float)b.y, c));
#endif
}

__device__ __forceinline__ float fast_tanh(float x) {
    const float e = __expf(2.0f * x);
    return 1.0f - 2.0f / (e + 1.0f);
}

__global__ __launch_bounds__(512, 2)
void nmrnn_kernel(
    const float* __restrict__ s, const float* __restrict__ c,
    const float* __restrict__ W_zz, const float* __restrict__ Wz_in,
    const float* __restrict__ bz_in, const float* __restrict__ Wz_out,
    const float* __restrict__ bz_out, const float* __restrict__ U,
    const float* __restrict__ V, const float* __restrict__ W_in,
    const float* __restrict__ b_in, const float* __restrict__ W_out,
    const float* __restrict__ b_out,
    float* __restrict__ out, float* __restrict__ states)
{
    __shared__ __align__(16) f16 tzh[DZ];       // tanh(z) f16
    __shared__ __align__(16) f16 sclh[64];      // [s_t|c_t] f16
    __shared__ __align__(16) float th[DH];      // tanh(h) f32
    __shared__ __align__(16) float redz[2][DZ]; // z-dot partials
    __shared__ __align__(16) float redh[2][DZ]; // W_in-dot partials
    __shared__ __align__(16) float wzo[RANK][DZ];
    __shared__ __align__(16) float vt[RANK][DH];  // V^T
    __shared__ __align__(16) float ut[RANK][DH];  // U^T
    __shared__ __align__(16) float wo[DY][DH];    // W_out
    __shared__ float gl[RANK];
    __shared__ float bo[DY];

    const int tid  = threadIdx.x;
    const int i    = tid & 255;
    const int q2   = tid >> 8;     // 0..1  K-half
    const int g    = tid >> 6;     // 0..7  wave
    const int l    = tid & 63;
    const int half = l >> 5;
    const int l32  = l & 31;
    const int b    = blockIdx.x;

    // ---- persistent f16-packed weights (88 VGPRs) ----
    h2 wzzp[64];
    #pragma unroll
    for (int m = 0; m < 32; ++m) {
        const float4 v4 = *(const float4*)&W_zz[i * 256 + (q2 << 7) + (m << 2)];
        wzzp[2 * m]     = pack2(v4.x, v4.y);
        wzzp[2 * m + 1] = pack2(v4.z, v4.w);
    }
    h2 wzip[16];
    #pragma unroll
    for (int m = 0; m < 8; ++m) {
        const float4 v4 = *(const float4*)&Wz_in[i * 64 + (q2 << 5) + (m << 2)];
        wzip[2 * m]     = pack2(v4.x, v4.y);
        wzip[2 * m + 1] = pack2(v4.z, v4.w);
    }
    h2 wip[8];
    #pragma unroll
    for (int m = 0; m < 4; ++m) {
        const float4 v4 = *(const float4*)&W_in[i * 32 + (q2 << 4) + (m << 2)];
        wip[2 * m]     = pack2(v4.x, v4.y);
        wip[2 * m + 1] = pack2(v4.z, v4.w);
    }

    // ---- stage small f32 matrices ----
    {   // Wz_out: 2048 floats
        const float4 v4 = *(const float4*)&Wz_out[tid * 4];
        *(float4*)&((float*)wzo)[tid * 4] = v4;
    }
    #pragma unroll
    for (int it = 0; it < 2; ++it) {  // W_out: 4096 floats
        const int idx = tid * 4 + it * 2048;
        *(float4*)&((float*)wo)[idx] = *(const float4*)&W_out[idx];
    }
    if (tid < 256) {
        #pragma unroll
        for (int r = 0; r < RANK; ++r) vt[r][tid] = V[tid * RANK + r];
        #pragma unroll
        for (int r = 0; r < RANK; ++r) ut[r][tid] = U[tid * RANK + r];
        tzh[tid] = (f16)0.f; th[tid] = 0.f;
    }
    if (tid < DY) bo[tid] = b_out[tid];

    const float bzi = (tid < 256) ? bz_in[i] : 0.f;
    const float bi  = (tid < 256) ? b_in[i]  : 0.f;
    float z_r = 0.f, h_r = 0.f;
    __syncthreads();   // staging done (wzo needed below)

    // ---- waves 4-7 persistent: rank rr, czb, rzb ----
    int rr = 0;
    float czb = 0.f, rzb = 0.f, hp = 0.f;
    if (g >= 4) {
        rr = ((g - 4) << 1) | half;
        float cz = 0.f;
        #pragma unroll
        for (int m = 0; m < 8; ++m) {
            const int k = l32 + 32 * m;
            cz = fmaf(bz_in[k], wzo[rr][k], cz);
        }
        #pragma unroll
        for (int off = 16; off >= 1; off >>= 1) cz += __shfl_xor(cz, off);
        const float bzo_r = bz_out[rr];
        czb = cz + bzo_r;
        rzb = bzo_r;
    }

    // t=0 inputs
    if (tid < 64) {
        const size_t base = (size_t)b * 32;
        sclh[tid] = (f16)((l < 32) ? s[base + l] : c[base + l - 32]);
    }
    __syncthreads();   // A0

    for (int t = 0; t < T_STEPS; ++t) {
        // ================= A..B =================
        float pfn = 0.f;
        if (tid < 64 && t + 1 < T_STEPS) {  // prefetch next inputs
            const size_t base = ((size_t)(t + 1) * BATCH + b) * 32;
            pfn = (l < 32) ? s[base + l] : c[base + l - 32];
        }

        // hp = tanh(h_{t-1}) @ V[:,rr]  (waves 4-7, 32-lane groups)
        if (g >= 4) {
            hp = 0.f;
            #pragma unroll
            for (int m = 0; m < 8; ++m) {
                const int k = l32 + 32 * m;
                hp = fmaf(th[k], vt[rr][k], hp);
            }
            #pragma unroll
            for (int off = 16; off >= 1; off >>= 1) hp += __shfl_xor(hp, off);
        }

        // out(t-1): 16 y-groups of 32 lanes, all waves
        if (t > 0) {
            const int y = (g << 1) | half;
            float o = 0.f;
            #pragma unroll
            for (int m = 0; m < 8; ++m) {
                const int k = l32 + 32 * m;
                o = fmaf(th[k], wo[y][k], o);
            }
            #pragma unroll
            for (int off = 16; off >= 1; off >>= 1) o += __shfl_xor(o, off);
            if (l32 == 0) out[((size_t)(t - 1) * BATCH + b) * 16 + y] = o + bo[y];
        }

        // dot2 partials: W_zz K-half + Wz_in + W_in (uniform LDS broadcasts)
        {
            float az = 0.f, ah = 0.f;
            const uint4* tz = (const uint4*)&tzh[q2 << 7];
            #pragma unroll
            for (int m = 0; m < 16; ++m) {
                const uint4 u = tz[m];
                az = dot2(wzzp[4 * m + 0], bc(u.x), az);
                az = dot2(wzzp[4 * m + 1], bc(u.y), az);
                az = dot2(wzzp[4 * m + 2], bc(u.z), az);
                az = dot2(wzzp[4 * m + 3], bc(u.w), az);
            }
            const uint4* sp = (const uint4*)&sclh[q2 << 5];
            #pragma unroll
            for (int m = 0; m < 4; ++m) {
                const uint4 u = sp[m];
                az = dot2(wzip[4 * m + 0], bc(u.x), az);
                az = dot2(wzip[4 * m + 1], bc(u.y), az);
                az = dot2(wzip[4 * m + 2], bc(u.z), az);
                az = dot2(wzip[4 * m + 3], bc(u.w), az);
            }
            const uint4* wp = (const uint4*)&sclh[q2 << 4];
            #pragma unroll
            for (int m = 0; m < 2; ++m) {
                const uint4 u = wp[m];
                ah = dot2(wip[4 * m + 0], bc(u.x), ah);
                ah = dot2(wip[4 * m + 1], bc(u.y), ah);
                ah = dot2(wip[4 * m + 2], bc(u.z), ah);
                ah = dot2(wip[4 * m + 3], bc(u.w), ah);
            }
            redz[q2][i] = az;
            redh[q2][i] = ah;
        }
        __syncthreads();  // B

        // ================= B..C =================
        if (tid < 256) {
            const float tmp = redz[0][i] + redz[1][i] + bzi;
            z_r = 0.99f * z_r + 0.01f * tmp;
            tzh[i] = (f16)fast_tanh(z_r);
            states[((size_t)t * BATCH + b) * 512 + i] = z_r;
        } else {
            float zp = 0.f;
            #pragma unroll
            for (int m = 0; m < 8; ++m) {
                const int k = l32 + 32 * m;
                zp = fmaf(redz[0][k] + redz[1][k], wzo[rr][k], zp);
            }
            #pragma unroll
            for (int off = 16; off >= 1; off >>= 1) zp += __shfl_xor(zp, off);
            rzb = 0.99f * rzb + 0.01f * (zp + czb);
            const float sg = 1.0f / (1.0f + __expf(-rzb));
            if (l32 == 0) gl[rr] = sg * hp;
        }
        __syncthreads();  // C

        // ================= C..A' =================
        if (tid < 256) {
            float tmp = redh[0][i] + redh[1][i] + bi;
            #pragma unroll
            for (int r = 0; r < RANK; ++r) tmp = fmaf(ut[r][i], gl[r], tmp);
            h_r = 0.9f * h_r + 0.1f * tmp;
            th[i] = fast_tanh(h_r);
            states[((size_t)t * BATCH + b) * 512 + 256 + i] = h_r;
        }
        if (tid < 64 && t + 1 < T_STEPS) sclh[tid] = (f16)pfn;
        __syncthreads();  // A
    }

    // ---- final out (t = T_STEPS-1) ----
    {
        const int y = (g << 1) | half;
        float o = 0.f;
        #pragma unroll
        for (int m = 0; m < 8; ++m) {
            const int k = l32 + 32 * m;
            o = fmaf(th[k], wo[y][k], o);
        }
        #pragma unroll
        for (int off = 16; off >= 1; off >>= 1) o += __shfl_xor(o, off);
        if (l32 == 0) out[((size_t)(T_STEPS - 1) * BATCH + b) * 16 + y] = o + bo[y];
    }
}

extern "C" void kernel_launch(void* const* d_in, const int* in_sizes, int n_in,
                              void* d_out, int out_size, void* d_ws, size_t ws_size,
                              hipStream_t stream) {
    const float* s     = (const float*)d_in[0];
    const float* c     = (const float*)d_in[1];
    const float* W_zz  = (const float*)d_in[2];
    const float* Wz_in = (const float*)d_in[3];
    const float* bz_in = (const float*)d_in[4];
    const float* Wz_out= (const float*)d_in[5];
    const float* bz_out= (const float*)d_in[6];
    const float* U     = (const float*)d_in[7];
    const float* V     = (const float*)d_in[8];
    const float* W_in  = (const float*)d_in[9];
    const float* b_in  = (const float*)d_in[10];
    const float* W_out = (const float*)d_in[11];
    const float* b_out = (const float*)d_in[12];

    float* out    = (float*)d_out;
    float* states = out + (size_t)T_STEPS * BATCH * DY;

    hipLaunchKernelGGL(nmrnn_kernel, dim3(BATCH), dim3(512), 0, stream,
                       s, c, W_zz, Wz_in, bz_in, Wz_out, bz_out, U, V,
                       W_in, b_in, W_out, b_out, out, states);
}